// Round 5
// baseline (563.885 us; speedup 1.0000x reference)
//
#include <hip/hip_runtime.h>
#include <hip/hip_bf16.h>
#include <math.h>

#define NB   16
#define NTOK 577
#define CDIM 768
#define NH   12
#define HID  3072
#define RTOT (NB*NTOK)        // 9232
#define MT   ((RTOT+127)/128) // 73
#define RPAD (MT*128)         // 9344
#define BH   (NB*NH)          // 192
#define QT   40               // 640/16 fragment-tiles per (b,h)

typedef __attribute__((ext_vector_type(8))) short bf16x8;
typedef __attribute__((ext_vector_type(4))) float f32x4;
typedef unsigned short u16;

__device__ inline void load_lds16(const void* g, void* l) {
    __builtin_amdgcn_global_load_lds(
        (const __attribute__((address_space(1))) unsigned*)g,
        (__attribute__((address_space(3))) unsigned*)l, 16, 0, 0);
}

// exp-based tanh gelu: one v_exp_f32 + one rcp; saturates cleanly (no NaN).
__device__ inline float fast_gelu(float x) {
    float y = 0.7978845608f * (x + 0.044715f * x * x * x);
    float e = __expf(2.0f * y);
    float th = 1.0f - 2.0f / (e + 1.0f);
    return 0.5f * x * (1.0f + th);
}

// ---------------------------------------------------------------------------
// Weight convert+transpose: src fp32 [K][N] -> dst bf16 [N][K]
// ---------------------------------------------------------------------------
__global__ __launch_bounds__(256) void wconvert(
    const float* __restrict__ src, __hip_bfloat16* __restrict__ dst,
    int K, int N)
{
    __shared__ float tile[64][65];
    int n0 = blockIdx.x * 64, k0 = blockIdx.y * 64;
    int c = threadIdx.x & 63, r = threadIdx.x >> 6;
    #pragma unroll 4
    for (int i = 0; i < 16; ++i)
        tile[r + i * 4][c] = src[(size_t)(k0 + r + i * 4) * N + n0 + c];
    __syncthreads();
    #pragma unroll 4
    for (int i = 0; i < 16; ++i)
        dst[(size_t)(n0 + r + i * 4) * K + k0 + c] =
            __float2bfloat16(tile[c][r + i * 4]);
}

// ---------------------------------------------------------------------------
// LayerNorm -> bf16
// ---------------------------------------------------------------------------
__global__ __launch_bounds__(256) void ln_kernel(
    const float* __restrict__ x, const float* __restrict__ g,
    const float* __restrict__ b, __hip_bfloat16* __restrict__ out)
{
    int row = blockIdx.x;
    const float* xr = x + (size_t)row * CDIM;
    __hip_bfloat16* orow = out + (size_t)row * CDIM;
    int t = threadIdx.x;
    float v0 = xr[t], v1 = xr[t + 256], v2 = xr[t + 512];
    float s  = v0 + v1 + v2;
    float s2 = v0*v0 + v1*v1 + v2*v2;
    #pragma unroll
    for (int off = 32; off; off >>= 1) {
        s  += __shfl_xor(s, off);
        s2 += __shfl_xor(s2, off);
    }
    __shared__ float red[10];
    int wave = t >> 6, lane = t & 63;
    if (lane == 0) { red[wave] = s; red[wave + 4] = s2; }
    __syncthreads();
    if (t == 0) {
        float ts  = red[0] + red[1] + red[2] + red[3];
        float ts2 = red[4] + red[5] + red[6] + red[7];
        float mu  = ts * (1.0f / CDIM);
        float var = ts2 * (1.0f / CDIM) - mu * mu;
        red[8] = mu;
        red[9] = rsqrtf(var + 1e-5f);
    }
    __syncthreads();
    float mu = red[8], rs = red[9];
    orow[t]       = __float2bfloat16((v0 - mu) * rs * g[t]       + b[t]);
    orow[t + 256] = __float2bfloat16((v1 - mu) * rs * g[t + 256] + b[t + 256]);
    orow[t + 512] = __float2bfloat16((v2 - mu) * rs * g[t + 512] + b[t + 512]);
}

// ---------------------------------------------------------------------------
// bf16 MFMA GEMM, BK=32, software-pipelined double buffer:
// ONE barrier per K-iteration; prefetch of tile k+1 issued before compute of
// tile k, so the vmcnt(0) drain at the next barrier overlaps with compute.
// flags: bit0=gelu, bit1=bf16 out. K must be a multiple of 32.
// ---------------------------------------------------------------------------
__global__ __launch_bounds__(256) void mfma_gemm(
    const __hip_bfloat16* __restrict__ A,
    const __hip_bfloat16* __restrict__ Bt,
    const float* __restrict__ bias, const float* __restrict__ res,
    void* __restrict__ outv, int M, int Nc, int K, int flags)
{
    __shared__ __align__(16) __hip_bfloat16 As[2][128 * 32];
    __shared__ __align__(16) __hip_bfloat16 Bs[2][128 * 32];
    int t = threadIdx.x;
    int lane = t & 63, wv = t >> 6;
    int m0 = blockIdx.y * 128, n0 = blockIdx.x * 128;

    const __hip_bfloat16* Ag = A  + (size_t)(m0 + (t >> 2)) * K + (t & 3) * 8;
    const __hip_bfloat16* Bg = Bt + (size_t)(n0 + (t >> 2)) * K + (t & 3) * 8;
    int ldso = wv * 512;

    int fr = lane & 15, fq = lane >> 4;
    int wm = (wv >> 1) * 64, wn = (wv & 1) * 64;

    f32x4 acc[4][4];
    #pragma unroll
    for (int i = 0; i < 4; ++i)
        #pragma unroll
        for (int j = 0; j < 4; ++j) acc[i][j] = (f32x4){0.f, 0.f, 0.f, 0.f};

    // prologue: stage tile 0 into buffer 0
    load_lds16(Ag,          As[0] + ldso);
    load_lds16(Ag + 64 * K, As[0] + ldso + 2048);
    load_lds16(Bg,          Bs[0] + ldso);
    load_lds16(Bg + 64 * K, Bs[0] + ldso + 2048);
    Ag += 32; Bg += 32;

    int ktiles = K >> 5;
    for (int k = 0; k < ktiles; ++k) {
        int cur = k & 1, nxt = cur ^ 1;
        __syncthreads();                    // tile k resident in As/Bs[cur]
        if (k + 1 < ktiles) {               // prefetch tile k+1 (in flight
            load_lds16(Ag,          As[nxt] + ldso);   // during compute)
            load_lds16(Ag + 64 * K, As[nxt] + ldso + 2048);
            load_lds16(Bg,          Bs[nxt] + ldso);
            load_lds16(Bg + 64 * K, Bs[nxt] + ldso + 2048);
            Ag += 32; Bg += 32;
        }
        const __hip_bfloat16* pa = As[cur] + (wm + fr) * 32 + fq * 8;
        const __hip_bfloat16* pb = Bs[cur] + (wn + fr) * 32 + fq * 8;
        bf16x8 af[4], bfv[4];
        #pragma unroll
        for (int tm = 0; tm < 4; ++tm)
            af[tm] = *(const bf16x8*)(pa + tm * 16 * 32);
        #pragma unroll
        for (int tn = 0; tn < 4; ++tn)
            bfv[tn] = *(const bf16x8*)(pb + tn * 16 * 32);
        #pragma unroll
        for (int tm = 0; tm < 4; ++tm)
            #pragma unroll
            for (int tn = 0; tn < 4; ++tn)
                acc[tm][tn] = __builtin_amdgcn_mfma_f32_16x16x32_bf16(
                    af[tm], bfv[tn], acc[tm][tn], 0, 0, 0);
    }

    float* outf = (float*)outv;
    __hip_bfloat16* outb = (__hip_bfloat16*)outv;
    int gelu = flags & 1, obf = flags & 2;
    #pragma unroll
    for (int tm = 0; tm < 4; ++tm) {
        #pragma unroll
        for (int rg = 0; rg < 4; ++rg) {
            int gm = m0 + wm + tm * 16 + fq * 4 + rg;
            if (gm >= M) continue;
            #pragma unroll
            for (int tn = 0; tn < 4; ++tn) {
                int gn = n0 + wn + tn * 16 + fr;
                float v = acc[tm][tn][rg] + bias[gn];
                if (gelu) v = fast_gelu(v);
                if (res)  v += res[(size_t)gm * Nc + gn];
                if (obf) outb[(size_t)gm * Nc + gn] = __float2bfloat16(v);
                else     outf[(size_t)gm * Nc + gn] = v;
            }
        }
    }
}

// ---------------------------------------------------------------------------
// Repack qkv (bf16 [RTOT][2304]) into fragment-ordered blobs.
// ---------------------------------------------------------------------------
__global__ __launch_bounds__(256) void repack_qk(
    const u16* __restrict__ qkv, u16* __restrict__ Qp, u16* __restrict__ Kp)
{
    __shared__ u16 blob[1024];
    int mt = blockIdx.x, bh = blockIdx.y, sec = blockIdx.z;
    int b = bh / NH, h = bh % NH;
    int t = threadIdx.x;
    int r = t >> 4, d = (t & 15) * 4;
    int row = mt * 16 + r;
    ushort4 v = make_ushort4(0, 0, 0, 0);
    if (row < NTOK)
        v = *(const ushort4*)(qkv + (size_t)(b * NTOK + row) * 2304 + sec * 768 + h * 64 + d);
    int kf = d >> 5, fq = (d >> 3) & 3, jj = d & 7;
    u16* p = blob + kf * 512 + (fq * 16 + r) * 8 + jj;
    p[0] = v.x; p[1] = v.y; p[2] = v.z; p[3] = v.w;
    __syncthreads();
    u16* dst = (sec == 0 ? Qp : Kp) + (size_t)(bh * QT + mt) * 1024;
    *(ushort4*)(dst + t * 4) = *(const ushort4*)(blob + t * 4);
}

// ---------------------------------------------------------------------------
// Repack V transposed.
// ---------------------------------------------------------------------------
__global__ __launch_bounds__(256) void repack_v(
    const u16* __restrict__ qkv, u16* __restrict__ Vp)
{
    __shared__ u16 blob[4096];
    int jt = blockIdx.x, bh = blockIdx.y;
    int b = bh / NH, h = bh % NH;
    int t = threadIdx.x;
    int d = (t & 15) * 4;
    int dt = d >> 4;
    #pragma unroll
    for (int it = 0; it < 4; ++it) {
        int jr = (t >> 4) + it * 16;
        int row = jt * 64 + jr;
        ushort4 v = make_ushort4(0, 0, 0, 0);
        if (row < NTOK)
            v = *(const ushort4*)(qkv + (size_t)(b * NTOK + row) * 2304 + 1536 + h * 64 + d);
        int jf = jr >> 5, fq = (jr >> 3) & 3, jj = jr & 7;
        u16* p = blob + (dt * 2 + jf) * 512 + (fq * 16 + (d & 15)) * 8 + jj;
        p[0] = v.x; p[8] = v.y; p[16] = v.z; p[24] = v.w;
    }
    __syncthreads();
    #pragma unroll
    for (int dd = 0; dd < 4; ++dd) {
        size_t dstoff = ((size_t)(bh * 4 + dd) * 20 + jt * 2) * 512;
        *(ushort4*)(Vp + dstoff + t * 4) = *(const ushort4*)(blob + dd * 1024 + t * 4);
    }
}

// ---------------------------------------------------------------------------
// MFMA flash attention.
// ---------------------------------------------------------------------------
__global__ __launch_bounds__(256) void attn_mfma(
    const u16* __restrict__ Qp, const u16* __restrict__ Kp,
    const u16* __restrict__ Vp, __hip_bfloat16* __restrict__ outp)
{
    __shared__ __align__(16) u16 Ks[4096];
    __shared__ __align__(16) u16 Vs[4096];
    __shared__ __align__(16) u16 Ps[4 * 16 * 72];

    int bh = blockIdx.y, qc = blockIdx.x;
    int b = bh / NH, h = bh % NH;
    int t = threadIdx.x, lane = t & 63, wv = t >> 6;
    int fr = lane & 15, fq = lane >> 4;

    int mt = qc * 4 + wv;
    const u16* qbase = Qp + (size_t)(bh * QT + mt) * 1024 + lane * 8;
    bf16x8 qf0 = *(const bf16x8*)(qbase);
    bf16x8 qf1 = *(const bf16x8*)(qbase + 512);

    const u16* kg = Kp + (size_t)bh * (QT * 1024) + wv * 1024 + lane * 8;
    const u16* vg = Vp + ((size_t)(bh * 4 + wv) * 20) * 512 + lane * 8;
    u16* lK  = Ks + wv * 1024;
    u16* lV  = Vs + wv * 1024;
    u16* psw = Ps + wv * (16 * 72);

    f32x4 o[4];
    float m_r[4], l_r[4];
    #pragma unroll
    for (int i = 0; i < 4; ++i) {
        o[i] = (f32x4){0.f, 0.f, 0.f, 0.f};
        m_r[i] = -1e30f; l_r[i] = 0.f;
    }

    for (int kt = 0; kt < 10; ++kt) {
        load_lds16(kg + kt * 4096,       lK);
        load_lds16(kg + kt * 4096 + 512, lK + 512);
        load_lds16(vg + kt * 1024,       lV);
        load_lds16(vg + kt * 1024 + 512, lV + 512);
        __syncthreads();

        f32x4 sc[4];
        #pragma unroll
        for (int nt = 0; nt < 4; ++nt) {
            sc[nt] = (f32x4){0.f, 0.f, 0.f, 0.f};
            bf16x8 kf0 = *(const bf16x8*)(Ks + (nt * 2 + 0) * 512 + lane * 8);
            bf16x8 kf1 = *(const bf16x8*)(Ks + (nt * 2 + 1) * 512 + lane * 8);
            sc[nt] = __builtin_amdgcn_mfma_f32_16x16x32_bf16(qf0, kf0, sc[nt], 0, 0, 0);
            sc[nt] = __builtin_amdgcn_mfma_f32_16x16x32_bf16(qf1, kf1, sc[nt], 0, 0, 0);
        }

        int j0 = kt * 64;
        float p[4][4], rm[4];
        #pragma unroll
        for (int rg = 0; rg < 4; ++rg) rm[rg] = -1e30f;
        #pragma unroll
        for (int nt = 0; nt < 4; ++nt) {
            bool valid = (j0 + nt * 16 + fr) < NTOK;
            #pragma unroll
            for (int rg = 0; rg < 4; ++rg) {
                float sv = valid ? sc[nt][rg] * 0.125f : -1e30f;
                p[nt][rg] = sv;
                rm[rg] = fmaxf(rm[rg], sv);
            }
        }
        #pragma unroll
        for (int rg = 0; rg < 4; ++rg) {
            #pragma unroll
            for (int off = 1; off < 16; off <<= 1)
                rm[rg] = fmaxf(rm[rg], __shfl_xor(rm[rg], off));
        }
        float alpha[4], rs[4];
        #pragma unroll
        for (int rg = 0; rg < 4; ++rg) {
            float mn = fmaxf(m_r[rg], rm[rg]);
            alpha[rg] = __expf(m_r[rg] - mn);
            m_r[rg] = mn;
            rs[rg] = 0.f;
        }
        #pragma unroll
        for (int nt = 0; nt < 4; ++nt)
            #pragma unroll
            for (int rg = 0; rg < 4; ++rg) {
                float pv = __expf(p[nt][rg] - m_r[rg]);
                p[nt][rg] = pv;
                rs[rg] += pv;
            }
        #pragma unroll
        for (int rg = 0; rg < 4; ++rg) {
            #pragma unroll
            for (int off = 1; off < 16; off <<= 1)
                rs[rg] += __shfl_xor(rs[rg], off);
            l_r[rg] = l_r[rg] * alpha[rg] + rs[rg];
        }

        #pragma unroll
        for (int nt = 0; nt < 4; ++nt)
            #pragma unroll
            for (int rg = 0; rg < 4; ++rg) {
                __hip_bfloat16 hb = __float2bfloat16(p[nt][rg]);
                psw[(fq * 4 + rg) * 72 + nt * 16 + fr] = *(u16*)&hb;
            }
        #pragma unroll
        for (int dt = 0; dt < 4; ++dt)
            #pragma unroll
            for (int rg = 0; rg < 4; ++rg)
                o[dt][rg] *= alpha[rg];

        bf16x8 pf0 = *(const bf16x8*)(psw + fr * 72 + fq * 8);
        bf16x8 pf1 = *(const bf16x8*)(psw + fr * 72 + 32 + fq * 8);
        #pragma unroll
        for (int dt = 0; dt < 4; ++dt) {
            bf16x8 bv0 = *(const bf16x8*)(Vs + (dt * 2 + 0) * 512 + lane * 8);
            bf16x8 bv1 = *(const bf16x8*)(Vs + (dt * 2 + 1) * 512 + lane * 8);
            o[dt] = __builtin_amdgcn_mfma_f32_16x16x32_bf16(pf0, bv0, o[dt], 0, 0, 0);
            o[dt] = __builtin_amdgcn_mfma_f32_16x16x32_bf16(pf1, bv1, o[dt], 0, 0, 0);
        }
        __syncthreads();
    }

    #pragma unroll
    for (int rg = 0; rg < 4; ++rg) {
        int row = qc * 64 + wv * 16 + fq * 4 + rg;
        if (row < NTOK) {
            float rl = 1.0f / l_r[rg];
            #pragma unroll
            for (int dt = 0; dt < 4; ++dt)
                outp[(size_t)(b * NTOK + row) * CDIM + h * 64 + dt * 16 + fr] =
                    __float2bfloat16(o[dt][rg] * rl);
        }
    }
}

// ---------------------------------------------------------------------------
extern "C" void kernel_launch(void* const* d_in, const int* in_sizes, int n_in,
                              void* d_out, int out_size, void* d_ws, size_t ws_size,
                              hipStream_t stream)
{
    const float* x      = (const float*)d_in[0];
    const float* ln1_g  = (const float*)d_in[1];
    const float* ln1_b  = (const float*)d_in[2];
    const float* w_qkv  = (const float*)d_in[3];
    const float* b_qkv  = (const float*)d_in[4];
    const float* w_proj = (const float*)d_in[5];
    const float* b_proj = (const float*)d_in[6];
    const float* ln2_g  = (const float*)d_in[7];
    const float* ln2_b  = (const float*)d_in[8];
    const float* w_fc1  = (const float*)d_in[9];
    const float* b_fc1  = (const float*)d_in[10];
    const float* w_fc2  = (const float*)d_in[11];
    const float* b_fc2  = (const float*)d_in[12];
    float* out = (float*)d_out;

    char* w = (char*)d_ws;
    __hip_bfloat16* wqkv_t = (__hip_bfloat16*)w; w += (size_t)3*CDIM*CDIM*2;
    __hip_bfloat16* wproj_t= (__hip_bfloat16*)w; w += (size_t)CDIM*CDIM*2;
    __hip_bfloat16* wfc1_t = (__hip_bfloat16*)w; w += (size_t)HID*CDIM*2;
    __hip_bfloat16* wfc2_t = (__hip_bfloat16*)w; w += (size_t)CDIM*HID*2;
    __hip_bfloat16* h_bf   = (__hip_bfloat16*)w; w += (size_t)RPAD*CDIM*2;
    __hip_bfloat16* h3_bf  = (__hip_bfloat16*)w; w += (size_t)RPAD*HID*2;
    u16*            qkv_bf = (u16*)w;            w += (size_t)RTOT*3*CDIM*2;
    u16*            Qp     = (u16*)w;            w += (size_t)BH*QT*1024*2;
    u16*            Kp     = (u16*)w;            w += (size_t)BH*QT*1024*2;
    u16*            Vp     = (u16*)w;            w += (size_t)BH*4*20*512*2;

    // 0. weights -> bf16 transposed [N][K]
    wconvert<<<dim3(3*CDIM/64, CDIM/64), 256, 0, stream>>>(w_qkv,  wqkv_t, CDIM, 3*CDIM);
    wconvert<<<dim3(CDIM/64,   CDIM/64), 256, 0, stream>>>(w_proj, wproj_t, CDIM, CDIM);
    wconvert<<<dim3(HID/64,    CDIM/64), 256, 0, stream>>>(w_fc1,  wfc1_t, CDIM, HID);
    wconvert<<<dim3(CDIM/64,   HID/64),  256, 0, stream>>>(w_fc2,  wfc2_t, HID, CDIM);

    // 1. h = LN1(x)
    ln_kernel<<<RTOT, 256, 0, stream>>>(x, ln1_g, ln1_b, h_bf);
    // 2. qkv = h @ w_qkv + b_qkv  (bf16 out)
    mfma_gemm<<<dim3(3*CDIM/128, MT), 256, 0, stream>>>(
        h_bf, wqkv_t, b_qkv, nullptr, qkv_bf, RTOT, 3*CDIM, CDIM, 2);
    // 3. fragment-pack q/k/v
    repack_qk<<<dim3(QT, BH, 2), 256, 0, stream>>>(qkv_bf, Qp, Kp);
    repack_v <<<dim3(10, BH),    256, 0, stream>>>(qkv_bf, Vp);
    // 4. attention -> h_bf
    attn_mfma<<<dim3(10, BH), 256, 0, stream>>>(Qp, Kp, Vp, h_bf);
    // 5. x1 = x + attnout @ w_proj + b_proj -> d_out (fp32)
    mfma_gemm<<<dim3(CDIM/128, MT), 256, 0, stream>>>(
        h_bf, wproj_t, b_proj, x, out, RTOT, CDIM, CDIM, 0);
    // 6. h = LN2(x1)
    ln_kernel<<<RTOT, 256, 0, stream>>>(out, ln2_g, ln2_b, h_bf);
    // 7. h3 = gelu(h @ w_fc1 + b_fc1)  (bf16 out)
    mfma_gemm<<<dim3(HID/128, MT), 256, 0, stream>>>(
        h_bf, wfc1_t, b_fc1, nullptr, h3_bf, RTOT, HID, CDIM, 1 | 2);
    // 8. out = x1 + h3 @ w_fc2 + b_fc2  (fp32, res==out same-thread)
    mfma_gemm<<<dim3(CDIM/128, MT), 256, 0, stream>>>(
        h3_bf, wfc2_t, b_fc2, out, out, RTOT, CDIM, HID, 0);
}